// Round 3
// baseline (650.701 us; speedup 1.0000x reference)
//
#include <hip/hip_runtime.h>
#include <math.h>

#define NEG_INF (-__builtin_inff())

// Top-2 semantics identical to jax.lax.top_k(x, 2).
// Branchless update; NEG_INF input is a no-op (safe padding).
__device__ __forceinline__ void top2_update(float v, float& m1, float& m2) {
    float nm1 = fmaxf(m1, v);
    m2 = fmaxf(m2, fminf(m1, v));
    m1 = nm1;
}

__device__ __forceinline__ void upd4(float4 v, float& m1, float& m2) {
    top2_update(v.x, m1, m2); top2_update(v.y, m1, m2);
    top2_update(v.z, m1, m2); top2_update(v.w, m1, m2);
}

// Tail-group update: branchless NEG_INF mask for inactive lanes.
__device__ __forceinline__ void upd4m(float4 v, bool act, float& m1, float& m2) {
    top2_update(act ? v.x : NEG_INF, m1, m2);
    top2_update(act ? v.y : NEG_INF, m1, m2);
    top2_update(act ? v.z : NEG_INF, m1, m2);
    top2_update(act ? v.w : NEG_INF, m1, m2);
}

// Merge two (top1, top2) pairs (each with m1 >= m2) into one.
__device__ __forceinline__ void top2_merge(float o1, float o2, float& m1, float& m2) {
    float hi = fmaxf(m1, o1);
    float lo = fminf(m1, o1);
    m2 = fmaxf(lo, fmaxf(m2, o2));
    m1 = hi;
}

// Monotonic unsigned encoding of float (order-preserving); enc(x) > 0 for all
// finite x, so a zeroed accumulator is a safe identity for atomicMax.
__device__ __forceinline__ unsigned int enc_float(float f) {
    unsigned int b = __float_as_uint(f);
    return (b & 0x80000000u) ? ~b : (b | 0x80000000u);
}

// One row's in-flight loads: target index first (so a wait on it leaves the
// 12 stream vectors outstanding), then 3 streams x 4 float4-groups.
struct Pending {
    int    tgt;
    float4 A0, A1, A2, A3;
    float4 B0, B1, B2, B3;
    float4 M0, M1, M2, M3;
};

__device__ __forceinline__ Pending issue_row(const float* __restrict__ out1,
                                             const float* __restrict__ out2,
                                             const float* __restrict__ mim,
                                             const int*   __restrict__ targets,
                                             int row, int lane, int tidx)
{
    const size_t base = (size_t)row * 1000u;
    const float4* p1 = (const float4*)(out1 + base);
    const float4* p2 = (const float4*)(out2 + base);
    const float4* p3 = (const float4*)(mim  + base);
    Pending P;
    P.tgt = targets[row];                 // issued FIRST (oldest outstanding)
    P.A0 = p1[lane]; P.A1 = p1[lane + 64]; P.A2 = p1[lane + 128]; P.A3 = p1[tidx];
    P.B0 = p2[lane]; P.B1 = p2[lane + 64]; P.B2 = p2[lane + 128]; P.B3 = p2[tidx];
    P.M0 = p3[lane]; P.M1 = p3[lane + 64]; P.M2 = p3[lane + 128]; P.M3 = p3[tidx];
    return P;
}

// C == 1000: 250 float4/row = 3 full 64-lane groups + 58-lane tail.
// 2-stage software pipeline across rows: a wave always has the NEXT row's
// 12 KB in flight while reducing the current row, so load duty-cycle ~100%
// (the rolled/batched versions sat at ~3 KB in flight and 3.85 TB/s effective).
__global__ __launch_bounds__(256) void margin_softmax_kernel(
    const float* __restrict__ out1,
    const float* __restrict__ out2,
    const float* __restrict__ mim,
    const int*   __restrict__ targets,
    float*       __restrict__ d_out,   // [0]=uint-encoded running max, [1+3*row+j]=softmax
    int N)
{
    const int C = 1000;
    const int lane          = threadIdx.x & 63;
    const int wave_in_blk   = threadIdx.x >> 6;
    const int waves_per_blk = blockDim.x >> 6;
    const int gwave  = blockIdx.x * waves_per_blk + wave_in_blk;
    const int nwaves = gridDim.x * waves_per_blk;
    // Tail group: lanes 58..63 re-load their group-0 address (guaranteed L1 hit,
    // no divergence) and are masked to NEG_INF at consume time.
    const int  tidx = (lane < 58) ? (lane + 192) : lane;
    const bool tact = (lane < 58);

    float lane_run = NEG_INF;   // running max over outputs1 & outputs2

    int row = gwave;
    Pending cur;
    if (row < N) cur = issue_row(out1, out2, mim, targets, row, lane, tidx);

    while (row < N) {
        const size_t base = (size_t)row * (size_t)C;

        // (1) Gathers for the CURRENT row. cur.tgt is the oldest outstanding
        //     load, so the wait drains only it; issued BEFORE next row's loads
        //     so consuming t1..t3 later never forces vmcnt(0) on the prefetch.
        const int tgt = cur.tgt;
        float t1 = out1[base + tgt];
        float t2 = out2[base + tgt];
        float t3 = mim [base + tgt];

        // (2) Prefetch the NEXT row (wave-uniform branch).
        const int nrow = row + nwaves;
        Pending nxt;
        if (nrow < N) nxt = issue_row(out1, out2, mim, targets, nrow, lane, tidx);

        // (3) Consume current row (loads issued a full iteration ago).
        float a1 = NEG_INF, a2 = NEG_INF;
        float b1 = NEG_INF, b2 = NEG_INF;
        float c1 = NEG_INF, c2 = NEG_INF;
        upd4(cur.A0, a1, a2); upd4(cur.A1, a1, a2); upd4(cur.A2, a1, a2); upd4m(cur.A3, tact, a1, a2);
        upd4(cur.B0, b1, b2); upd4(cur.B1, b1, b2); upd4(cur.B2, b1, b2); upd4m(cur.B3, tact, b1, b2);
        upd4(cur.M0, c1, c2); upd4(cur.M1, c1, c2); upd4(cur.M2, c1, c2); upd4m(cur.M3, tact, c1, c2);

        // (4) 64-lane butterfly reduce of the three (top1, top2) pairs;
        //     overlaps the in-flight t1..t3 gathers.
        #pragma unroll
        for (int off = 32; off >= 1; off >>= 1) {
            float o1, o2;
            o1 = __shfl_xor(a1, off); o2 = __shfl_xor(a2, off); top2_merge(o1, o2, a1, a2);
            o1 = __shfl_xor(b1, off); o2 = __shfl_xor(b2, off); top2_merge(o1, o2, b1, b2);
            o1 = __shfl_xor(c1, off); o2 = __shfl_xor(c2, off); top2_merge(o1, o2, c1, c2);
        }

        lane_run = fmaxf(lane_run, fmaxf(a1, b1));

        // (5) Margins + softmax + store.
        if (lane == 0) {
            // margin = (tgt_logit == top1) ? top1 - top2 : 0 (exact fp equality,
            // same float values as the reference computes)
            float d1 = (t1 == a1) ? (a1 - a2) : 0.0f;
            float d2 = (t2 == b1) ? (b1 - b2) : 0.0f;
            float d3 = (t3 == c1) ? (c1 - c2) : 0.0f;
            float x1 = d1 * 0.5f, x2 = d2 * 0.5f, x3 = d3 * 0.5f;  // /T, T=2
            float mx = fmaxf(x1, fmaxf(x2, x3));
            float e1 = expf(x1 - mx), e2 = expf(x2 - mx), e3 = expf(x3 - mx);
            float inv = 1.0f / (e1 + e2 + e3);
            float* o = d_out + 1 + (size_t)row * 3;
            o[0] = e1 * inv;
            o[1] = e2 * inv;
            o[2] = e3 * inv;
        }

        row = nrow;
        cur = nxt;   // rotate pipeline (dissolves into SSA copies)
    }

    // Reduce lane_run across wave -> block -> one atomic per block.
    #pragma unroll
    for (int off = 32; off >= 1; off >>= 1)
        lane_run = fmaxf(lane_run, __shfl_xor(lane_run, off));

    __shared__ float smax[8];
    if (lane == 0) smax[wave_in_blk] = lane_run;
    __syncthreads();
    if (threadIdx.x == 0) {
        float m = smax[0];
        for (int i = 1; i < waves_per_blk; i++) m = fmaxf(m, smax[i]);
        atomicMax((unsigned int*)d_out, enc_float(m));
    }
}

__global__ void finalize_max_kernel(float* d_out) {
    unsigned int u = ((unsigned int*)d_out)[0];
    unsigned int b = (u & 0x80000000u) ? (u ^ 0x80000000u) : ~u;
    d_out[0] = __uint_as_float(b);
}

extern "C" void kernel_launch(void* const* d_in, const int* in_sizes, int n_in,
                              void* d_out, int out_size, void* d_ws, size_t ws_size,
                              hipStream_t stream) {
    const float* out1    = (const float*)d_in[0];
    const float* out2    = (const float*)d_in[1];
    const float* mim     = (const float*)d_in[2];
    const int*   targets = (const int*)  d_in[3];

    const int N = in_sizes[3];            // 65536 (C fixed at 1000 in the kernel)

    // d_out[0] doubles as the uint atomicMax accumulator; enc(x) > 0 for all
    // finite x, so zero is the identity. Decoded in-place by the epilogue.
    (void)hipMemsetAsync(d_out, 0, sizeof(unsigned int), stream);

    // 2048 blocks x 256 threads = 8192 waves; 8 pipelined rows per wave.
    margin_softmax_kernel<<<2048, 256, 0, stream>>>(
        out1, out2, mim, targets, (float*)d_out, N);

    finalize_max_kernel<<<1, 1, 0, stream>>>((float*)d_out);
}